// Round 1
// 76.574 us; speedup vs baseline: 1.0004x; 1.0004x over previous
//
#include <hip/hip_runtime.h>
#include <math.h>

#define NP   196   // 14*14 patches per image
#define FEAT 784
#define IPB  4     // images per block

// Fully fused: conv2x2/s2 -> 4-qubit quantum filter -> FC(784->10) -> log_softmax.
// One block (256 threads) per 4 images: grid = B/4 = 1024 blocks = exactly
// 4 blocks/CU on 256 CUs -> the whole kernel is ONE co-resident batch.
//
// Circuit algebra (verified against reference op order):
//   enc RY(x_w) ; RY0(a0) RY1(a1) CNOT(0,1) RY2(a2) CNOT(1,2) RY3(a3)
//   CNOT(2,3) RY0(a4)
// == product state with theta_w = x_w + a_w  ->  CNOT(0,1) CNOT(1,2) CNOT(2,3)
//    -> RY0(a4) -> measure Z.
// The final RY0 is folded into measurement: per wire-0 pair (u,v),
//   <Z0> contrib = cos(a4)(u^2-v^2) - sin(a4)*2uv;  Z1..Z3 invariant.
// CNOTs are compile-time index renames (zero VALU).

__device__ __forceinline__ void apply_cnot(float* s, const int mc, const int mt) {
#pragma unroll
    for (int i = 0; i < 16; ++i) {
        if ((i & mc) && !(i & mt)) {
            float t = s[i];
            s[i]      = s[i | mt];
            s[i | mt] = t;
        }
    }
}

__global__ void __launch_bounds__(256, 4)
quanv_fused(const float* __restrict__ x,    // [B,1,28,28]
            const float* __restrict__ cw,   // [4,1,2,2]
            const float* __restrict__ cb,   // [4]
            const float* __restrict__ ang,  // [5]
            const float* __restrict__ W,    // [10,784]
            const float* __restrict__ bias, // [10]
            float* __restrict__ out,        // [B,10]
            const int B) {
    __shared__ float feats[IPB][FEAT];

    const int tid = threadIdx.x;
    const int b0  = blockIdx.x * IPB;

    // ---------------- Phase 1: conv + quantum filter ----------------
    // 784 patch-computations (4 images x 196 patches) over 256 threads.
    // p = tid + 256*r : r=0..2 always valid, r=3 only for tid<16.
    // Loads hoisted (static r-index -> stays in VGPRs) so the 4 HBM
    // round-trips overlap the trig-heavy compute.
    float2 r0v[4], r1v[4];
#pragma unroll
    for (int r = 0; r < 4; ++r) {
        const int p = tid + 256 * r;
        if (p < IPB * NP) {
            const int im = p / NP;
            const int k  = p - im * NP;
            const int i  = k / 14;
            const int j  = k - i * 14;
            int img = b0 + im;
            if (img >= B) img = B - 1;  // safety clamp (B=4096: never taken)
            const float* xp = x + img * 784 + (2 * i) * 28 + 2 * j;
            r0v[r] = *(const float2*)(xp);
            r1v[r] = *(const float2*)(xp + 28);
        }
    }

#pragma unroll
    for (int r = 0; r < 4; ++r) {
        const int p = tid + 256 * r;
        if (p < IPB * NP) {
            const int im = p / NP;
            const int k  = p - im * NP;
            const float2 r0 = r0v[r];
            const float2 r1 = r1v[r];

            // theta_w = conv_w(patch) + cb_w + ang_w (RY merge), half-angle sincos
            float cs[4], sn[4];
#pragma unroll
            for (int c = 0; c < 4; ++c) {
                float th = cw[c * 4 + 0] * r0.x + cw[c * 4 + 1] * r0.y +
                           cw[c * 4 + 2] * r1.x + cw[c * 4 + 3] * r1.y +
                           (cb[c] + ang[c]);
                __sincosf(0.5f * th, &sn[c], &cs[c]);
            }

            // product state: bit3=q0, bit2=q1, bit1=q2, bit0=q3
            float s[16];
            {
                float v00 = cs[0] * cs[1], v01 = cs[0] * sn[1];
                float v10 = sn[0] * cs[1], v11 = sn[0] * sn[1];
                float w00 = cs[2] * cs[3], w01 = cs[2] * sn[3];
                float w10 = sn[2] * cs[3], w11 = sn[2] * sn[3];
                s[ 0] = v00 * w00; s[ 1] = v00 * w01; s[ 2] = v00 * w10; s[ 3] = v00 * w11;
                s[ 4] = v01 * w00; s[ 5] = v01 * w01; s[ 6] = v01 * w10; s[ 7] = v01 * w11;
                s[ 8] = v10 * w00; s[ 9] = v10 * w01; s[10] = v10 * w10; s[11] = v10 * w11;
                s[12] = v11 * w00; s[13] = v11 * w01; s[14] = v11 * w10; s[15] = v11 * w11;
            }

            // CNOT(0,1), CNOT(1,2), CNOT(2,3) — register renames when unrolled
            apply_cnot(s, 8, 4);
            apply_cnot(s, 4, 2);
            apply_cnot(s, 2, 1);

            // measurement with final RY0(a4) folded in
            float pr[16];
#pragma unroll
            for (int idx = 0; idx < 16; ++idx) pr[idx] = s[idx] * s[idx];

            float q[8], d[8], xx[8];
#pragma unroll
            for (int jj = 0; jj < 8; ++jj) {
                q[jj]  = pr[jj] + pr[jj + 8];      // pair probability (RY0-invariant)
                d[jj]  = pr[jj] - pr[jj + 8];      // u^2 - v^2
                xx[jj] = s[jj] * s[jj + 8];        // u*v
            }

            float A = q[0] + q[1], Bq = q[2] + q[3], C = q[4] + q[5], D = q[6] + q[7];
            float ez1 = (A + Bq) - (C + D);
            float ez2 = (A - Bq) + (C - D);
            float ez3 = (q[0] - q[1]) + (q[2] - q[3]) + (q[4] - q[5]) + (q[6] - q[7]);

            float Dsum = ((d[0] + d[1]) + (d[2] + d[3])) + ((d[4] + d[5]) + (d[6] + d[7]));
            float Xsum = ((xx[0] + xx[1]) + (xx[2] + xx[3])) + ((xx[4] + xx[5]) + (xx[6] + xx[7]));
            float ca4, sa4;
            __sincosf(ang[4], &sa4, &ca4);
            float ez0 = ca4 * Dsum - sa4 * (2.0f * Xsum);

            feats[im][0 * NP + k] = ez0;
            feats[im][1 * NP + k] = ez1;
            feats[im][2 * NP + k] = ez2;
            feats[im][3 * NP + k] = ez3;
        }
    }

    __syncthreads();

    // ---------------- Phase 2: FC 784->10 + log_softmax ----------------
    // Wave wv handles image b0+wv: all 256 lanes busy, W lines hit L1 4x.
    const int wv   = tid >> 6;
    const int lane = tid & 63;

    float acc[10];
#pragma unroll
    for (int k = 0; k < 10; ++k) acc[k] = 0.f;

    const float* fr = feats[wv];
    for (int c = lane; c < NP; c += 64) {
        const float4 f = *(const float4*)&fr[c * 4];
        const float* wp = W + c * 4;
#pragma unroll
        for (int k = 0; k < 10; ++k) {
            const float4 w = *(const float4*)(wp + k * FEAT);
            acc[k] += fmaf(f.x, w.x, fmaf(f.y, w.y, fmaf(f.z, w.z, f.w * w.w)));
        }
    }

#pragma unroll
    for (int k = 0; k < 10; ++k) {
#pragma unroll
        for (int off = 32; off > 0; off >>= 1)
            acc[k] += __shfl_down(acc[k], off, 64);
    }

    const int img = b0 + wv;
    if (lane == 0 && img < B) {
        float l[10], m = -INFINITY;
#pragma unroll
        for (int k = 0; k < 10; ++k) {
            l[k] = acc[k] + bias[k];
            m = fmaxf(m, l[k]);
        }
        float ssum = 0.f;
#pragma unroll
        for (int k = 0; k < 10; ++k) ssum += __expf(l[k] - m);
        float ls = __logf(ssum) + m;
        float* o = out + img * 10;
#pragma unroll
        for (int k = 0; k < 10; ++k) o[k] = l[k] - ls;
    }
}

extern "C" void kernel_launch(void* const* d_in, const int* in_sizes, int n_in,
                              void* d_out, int out_size, void* d_ws, size_t ws_size,
                              hipStream_t stream) {
    const float* x      = (const float*)d_in[0];
    const float* conv_w = (const float*)d_in[1];
    const float* conv_b = (const float*)d_in[2];
    const float* angles = (const float*)d_in[3];
    const float* fc_w   = (const float*)d_in[4];
    const float* fc_b   = (const float*)d_in[5];
    float* out = (float*)d_out;

    int B  = in_sizes[0] / 784;            // 4096
    int nb = (B + IPB - 1) / IPB;          // 1024 blocks = 4/CU, all co-resident
    quanv_fused<<<nb, 256, 0, stream>>>(x, conv_w, conv_b, angles, fc_w, fc_b, out, B);
}